// Round 4
// baseline (130.743 us; speedup 1.0000x reference)
//
#include <hip/hip_runtime.h>
#include <hip/hip_bf16.h>
#include <stdint.h>

typedef short s16x8 __attribute__((ext_vector_type(8)));
typedef float f32x4 __attribute__((ext_vector_type(4)));

static constexpr int DDIM = 256;
static constexpr float TEN_LOG2E = 14.4269504088896340736f; // 10 * log2(e)

using u32_glb = __attribute__((address_space(1))) unsigned int;
using u32_lds = __attribute__((address_space(3))) unsigned int;

// ---------------- Kernel 1: normalize + pack into MFMA-fragment order ----------------
// 512 blocks x 256 threads; block g handles rows [16g, 16g+16). Output layout:
// packed[((g*8 + kt)*64 + lane)*8 .. +8] = bf16 P[16g + (lane&15)][kt*32 + (lane>>4)*8 ..]
// Each (group, kt) fragment is one contiguous 1KB block in exact lane order.
// Also zero-inits row_s[8192] (blocks 0..7) and out[0] (block 0).
__global__ __launch_bounds__(256) void normalize_pack_kernel(
    const float* __restrict__ zi, const float* __restrict__ zj,
    ushort* __restrict__ packed, float* __restrict__ row_s, float* __restrict__ out)
{
    __shared__ ushort lds[16 * 256];

    if (blockIdx.x < 8) {
        ((float4*)row_s)[blockIdx.x * 256 + threadIdx.x] = (float4){0.f, 0.f, 0.f, 0.f};
        if (blockIdx.x == 0 && threadIdx.x == 0) out[0] = 0.0f;
    }

    const int t = threadIdx.x;
    const int r = t >> 4;            // 0..15: row within group
    const int c = t & 15;            // 16 threads per row
    const int row = blockIdx.x * 16 + r;
    const float* src = (row < 4096) ? (zi + (size_t)row * DDIM)
                                    : (zj + (size_t)(row - 4096) * DDIM);
    float4 v[4];
    #pragma unroll
    for (int j = 0; j < 4; ++j) v[j] = ((const float4*)src)[c + j * 16];

    float ss = 0.0f;
    #pragma unroll
    for (int j = 0; j < 4; ++j)
        ss += v[j].x * v[j].x + v[j].y * v[j].y + v[j].z * v[j].z + v[j].w * v[j].w;
    ss += __shfl_xor(ss, 1, 64);
    ss += __shfl_xor(ss, 2, 64);
    ss += __shfl_xor(ss, 4, 64);
    ss += __shfl_xor(ss, 8, 64);
    const float inv = 1.0f / fmaxf(sqrtf(ss), 1e-8f);

    #pragma unroll
    for (int j = 0; j < 4; ++j) {
        ushort4 o;
        o.x = __builtin_bit_cast(unsigned short, __float2bfloat16(v[j].x * inv));
        o.y = __builtin_bit_cast(unsigned short, __float2bfloat16(v[j].y * inv));
        o.z = __builtin_bit_cast(unsigned short, __float2bfloat16(v[j].z * inv));
        o.w = __builtin_bit_cast(unsigned short, __float2bfloat16(v[j].w * inv));
        *(ushort4*)(lds + r * 256 + (c + j * 16) * 4) = o;
    }
    __syncthreads();

    #pragma unroll
    for (int h = 0; h < 2; ++h) {
        const int idx  = h * 256 + t;
        const int kt   = idx >> 6;
        const int lane = idx & 63;
        const int q    = lane >> 4;
        const int l15  = lane & 15;
        s16x8 frag = *(const s16x8*)(lds + l15 * 256 + kt * 32 + q * 8);
        ((s16x8*)packed)[(size_t)(blockIdx.x * 8 + kt) * 64 + lane] = frag;
    }
}

// ---------------- Kernel 2: persistent 4-tile blocks, ring-4 depth-3 pipeline --------
// 520 blocks x 4 consecutive tiles each (2080 = 520*4). The k-step stream (32 steps)
// runs continuously through a ring of 4 LDS buffers, prefetch depth 3: stage(s+3)
// issued at step s, counted s_waitcnt vmcnt(8) before each raw s_barrier (the two
// newest stage-groups stay in flight; in-order vmcnt retirement makes the fixed-N
// wait retire everything older, including any epilogue VMEM writes, so the waits
// stay conservative even though atomics/stores inflate the counter). Tile epilogues
// do NOT drain vmcnt — the next tile's kt=0..2 loads (issued at kt=5..7) fly through
// the ~1.5k-cycle exp/reduce epilogue, hiding the cold-start that killed the
// one-tile-per-block versions. sched_barrier(0) after each waitcnt/barrier pins the
// stage-issue order (a hoisted stage would overwrite the slot read at kt-1).
// Per-wave partials to disjoint LDS; one global atomic per row/col per tile.
__global__ __launch_bounds__(256) void simexp_kernel(
    const ushort* __restrict__ packed,
    float* __restrict__ row_s,
    float* __restrict__ pos_out)
{
    __shared__ ushort sbuf[4][16][512];   // 64 KB ring: frags 0..7 = A, 8..15 = B
    __shared__ float rsum_lds[4][64];     // per-wave row partials
    __shared__ float csum_lds[4][64];     // per-wave col partials

    const int tid  = threadIdx.x;
    const int w    = tid >> 6;
    const int lane = tid & 63;
    const int q    = lane >> 4;
    const int l15  = lane & 15;
    const int wm   = (w >> 1) * 64;
    const int wn   = (w & 1) * 64;

    constexpr int NT = 4;

    // ---- decode first tile: block p owns tiles b0..b0+3 (upper triangle, ti<=tj) ----
    const int b0 = blockIdx.x * NT;
    int ti = (int)(64.5f - sqrtf(64.5f * 64.5f - 2.0f * (float)b0));
    while ((ti + 1) * 64 - ((ti + 1) * ti) / 2 <= b0) ++ti;
    while (ti * 64 - (ti * (ti - 1)) / 2 > b0) --ti;
    int cti = ti, ctj = ti + (b0 - (ti * 64 - (ti * (ti - 1)) / 2));

    const ushort* curb[4];
    const ushort* nxtb[4];
    auto mkbase = [&](const ushort** dst, int tti, int ttj) {
        #pragma unroll
        for (int si = 0; si < 4; ++si) {
            const int f = w * 4 + si;
            const int g = (f < 8) ? (tti * 8 + f) : (ttj * 8 + (f - 8));
            dst[si] = packed + (size_t)g * 4096 + (size_t)lane * 8;
        }
    };
    mkbase(curb, cti, ctj);

    auto stage = [&](int slot, const ushort* const* bb, int kk) {
        #pragma unroll
        for (int si = 0; si < 4; ++si) {
            const int f = w * 4 + si;
            __builtin_amdgcn_global_load_lds(
                (const u32_glb*)(bb[si] + kk * 512),
                (u32_lds*)&sbuf[slot][f][0], 16, 0, 0);
        }
    };

    f32x4 acc[4][4];
    #pragma unroll
    for (int mi = 0; mi < 4; ++mi)
        #pragma unroll
        for (int ni = 0; ni < 4; ++ni)
            acc[mi][ni] = (f32x4){0.f, 0.f, 0.f, 0.f};

    // prologue: fill ring slots 0..2 (steps 0,1,2); wait for step 0's 4 loads only
    stage(0, curb, 0);
    stage(1, curb, 1);
    stage(2, curb, 2);
    asm volatile("s_waitcnt vmcnt(8)" ::: "memory");
    __builtin_amdgcn_sched_barrier(0);
    __builtin_amdgcn_s_barrier();
    __builtin_amdgcn_sched_barrier(0);

    const int fa0 = (w >> 1) * 4;
    const int fb0 = 8 + (w & 1) * 4;

    int nti = cti, ntj = ctj;

    #pragma unroll 1
    for (int t = 0; t < NT; ++t) {
        if (t + 1 < NT) {
            if (ctj == 63) { nti = cti + 1; ntj = nti; }
            else           { nti = cti;     ntj = ctj + 1; }
            mkbase(nxtb, nti, ntj);
        }
        const int r0 = cti * 128, c0 = ctj * 128;
        const bool diag  = (cti == ctj);
        const bool ptile = (ctj == cti + 32);
        const bool last  = (t == NT - 1);

        #pragma unroll
        for (int kt = 0; kt < 8; ++kt) {
            // stage step s+3 into slot (kt+3)&3; crosses into next tile at kt>=5
            if (kt < 5)       stage((kt + 3) & 3, curb, kt + 3);
            else if (!last)   stage((kt + 3) & 3, nxtb, kt - 5);

            s16x8 af[4], bfr[4];
            #pragma unroll
            for (int mi = 0; mi < 4; ++mi)
                af[mi] = *(const s16x8*)&sbuf[kt & 3][fa0 + mi][lane * 8];
            #pragma unroll
            for (int ni = 0; ni < 4; ++ni)
                bfr[ni] = *(const s16x8*)&sbuf[kt & 3][fb0 + ni][lane * 8];

            #pragma unroll
            for (int mi = 0; mi < 4; ++mi)
                #pragma unroll
                for (int ni = 0; ni < 4; ++ni)
                    acc[mi][ni] = __builtin_amdgcn_mfma_f32_16x16x32_bf16(
                        af[mi], bfr[ni], acc[mi][ni], 0, 0, 0);

            // counted wait: retires through step s+1's loads (oldest outstanding);
            // the two newest stage-groups stay in flight across the barrier.
            if (!last || kt < 5)      asm volatile("s_waitcnt vmcnt(8)" ::: "memory");
            else if (kt == 5)         asm volatile("s_waitcnt vmcnt(4)" ::: "memory");
            else if (kt == 6)         asm volatile("s_waitcnt vmcnt(0)" ::: "memory");
            __builtin_amdgcn_sched_barrier(0);
            if (!last || kt < 7) {
                __builtin_amdgcn_s_barrier();
                __builtin_amdgcn_sched_barrier(0);
            }
        }

        // ---- per-tile epilogue: exp, masks, positive pairs, row/col partials ----
        // C/D layout (16x16): col = lane&15, row = q*4 + r
        float rsum[4][4];
        float csum[4] = {0.f, 0.f, 0.f, 0.f};
        #pragma unroll
        for (int mi = 0; mi < 4; ++mi)
            #pragma unroll
            for (int r = 0; r < 4; ++r) rsum[mi][r] = 0.0f;

        #pragma unroll
        for (int mi = 0; mi < 4; ++mi)
            #pragma unroll
            for (int ni = 0; ni < 4; ++ni)
                #pragma unroll
                for (int r = 0; r < 4; ++r) {
                    const int lr = wm + mi * 16 + q * 4 + r;
                    const int lc = wn + ni * 16 + l15;
                    float e = exp2f(acc[mi][ni][r] * TEN_LOG2E);
                    if (diag && lr == lc) e = 0.0f;
                    rsum[mi][r] += e;
                    csum[ni]    += e;
                    if (ptile && lr == lc) {
                        const float v = acc[mi][ni][r] * 10.0f;
                        pos_out[r0 + lr] = v;
                        pos_out[c0 + lr] = v;
                    }
                    acc[mi][ni][r] = 0.0f;   // reset for next tile
                }

        // row partials: reduce across 16 cols; lanes l15==0 hold 16 rows per wave
        #pragma unroll
        for (int mi = 0; mi < 4; ++mi)
            #pragma unroll
            for (int r = 0; r < 4; ++r) {
                float v = rsum[mi][r];
                v += __shfl_xor(v, 1, 64);
                v += __shfl_xor(v, 2, 64);
                v += __shfl_xor(v, 4, 64);
                v += __shfl_xor(v, 8, 64);
                if (l15 == 0) rsum_lds[w][mi * 16 + q * 4 + r] = v;
            }
        // col partials: reduce across 4 row-quads; lanes 0..15 hold 16 cols per wave
        #pragma unroll
        for (int ni = 0; ni < 4; ++ni) {
            float v = csum[ni];
            v += __shfl_xor(v, 16, 64);
            v += __shfl_xor(v, 32, 64);
            if (lane < 16) csum_lds[w][ni * 16 + l15] = v;
        }

        // raw barrier: lgkm only — staged global_load_lds for the next tile stay in flight
        asm volatile("s_waitcnt lgkmcnt(0)" ::: "memory");
        __builtin_amdgcn_sched_barrier(0);
        __builtin_amdgcn_s_barrier();
        __builtin_amdgcn_sched_barrier(0);

        // combine wave pairs; one global atomic per row / per col (wave-uniform branches)
        if (tid < 128) {
            const float v = rsum_lds[(tid >> 6) * 2][tid & 63]
                          + rsum_lds[(tid >> 6) * 2 + 1][tid & 63];
            atomicAdd(&row_s[r0 + tid], v);
        } else if (!diag) {
            const int c = tid - 128;
            const float v = (c < 64) ? (csum_lds[0][c] + csum_lds[2][c])
                                     : (csum_lds[1][c - 64] + csum_lds[3][c - 64]);
            atomicAdd(&row_s[c0 + c], v);
        }
        // next epilogue's LDS writes are >=7 barriers away: no extra barrier needed

        cti = nti; ctj = ntj;
        #pragma unroll
        for (int si = 0; si < 4; ++si) curb[si] = nxtb[si];
    }
}

// ---------------- Kernel 3: finalize loss ----------------
__global__ __launch_bounds__(256) void finalize_kernel(
    const float* __restrict__ row_s, const float* __restrict__ pos,
    float* __restrict__ out)
{
    const int i = blockIdx.x * 256 + threadIdx.x;   // float4 index, 2048 total
    float4 s = ((const float4*)row_s)[i];
    float4 p = ((const float4*)pos)[i];
    float local = (__logf(s.x) - p.x) + (__logf(s.y) - p.y)
                + (__logf(s.z) - p.z) + (__logf(s.w) - p.w);
    #pragma unroll
    for (int off = 32; off > 0; off >>= 1) local += __shfl_xor(local, off, 64);
    __shared__ float red[4];
    if ((threadIdx.x & 63) == 0) red[threadIdx.x >> 6] = local;
    __syncthreads();
    if (threadIdx.x == 0)
        atomicAdd(out, (red[0] + red[1] + red[2] + red[3]) * (1.0f / 8192.0f));
}

// ---------------- Launch ----------------
extern "C" void kernel_launch(void* const* d_in, const int* in_sizes, int n_in,
                              void* d_out, int out_size, void* d_ws, size_t ws_size,
                              hipStream_t stream)
{
    const float* zi = (const float*)d_in[0];
    const float* zj = (const float*)d_in[1];

    ushort* packed = (ushort*)d_ws;                                    // 4 MB fragment-order bf16
    float* row_s   = (float*)((char*)d_ws + (4u << 20));               // 8192 fp32
    float* pos     = (float*)((char*)d_ws + (4u << 20) + (32u << 10)); // 8192 fp32
    float* out     = (float*)d_out;

    hipLaunchKernelGGL(normalize_pack_kernel, dim3(512), dim3(256), 0, stream,
                       zi, zj, packed, row_s, out);
    hipLaunchKernelGGL(simexp_kernel, dim3(520), dim3(256), 0, stream,
                       packed, row_s, pos);
    hipLaunchKernelGGL(finalize_kernel, dim3(8), dim3(256), 0, stream, row_s, pos, out);
}